// Round 3
// baseline (1554.008 us; speedup 1.0000x reference)
//
#include <hip/hip_runtime.h>
#include <hip/hip_bf16.h>

#define HEADS 4
#define C 32
#define OUTCH 128   // HEADS*C
#define INCH 128
#define NEG_SLOPE 0.2f

#define BKT 64        // dst nodes per bucket
#define BKT_BITS 6
#define SBL 256       // scatter blocks

// ---------------------------------------------------------------------------
// per-(bucket,block) histogram — no global atomics
// ---------------------------------------------------------------------------
__global__ __launch_bounds__(256) void k_hist(const int* __restrict__ dst,
                                              int* __restrict__ hist,
                                              int E, int NB, int chunk) {
    __shared__ int lh[1024];
    int blk = blockIdx.x;
    for (int i = threadIdx.x; i < NB; i += 256) lh[i] = 0;
    __syncthreads();
    int beg = blk * chunk, end = min(E, beg + chunk);
    for (int e = beg + threadIdx.x; e < end; e += 256)
        atomicAdd(&lh[dst[e] >> BKT_BITS], 1);
    __syncthreads();
    // XCD-major column so adjacent segments come from same-XCD blocks
    int cm = (blk & 7) * (SBL / 8) + (blk >> 3);
    for (int b = threadIdx.x; b < NB; b += 256) hist[b * SBL + cm] = lh[b];
}

// ---------------------------------------------------------------------------
// scan over NB*SBL entries (3 kernels)
// ---------------------------------------------------------------------------
__global__ __launch_bounds__(1024) void k_scan1(const int* __restrict__ v,
                                                int* __restrict__ incl,
                                                int* __restrict__ bsum, int n) {
    __shared__ int sm[1024];
    int t = threadIdx.x;
    int g = blockIdx.x * 1024 + t;
    int x = (g < n) ? v[g] : 0;
    sm[t] = x;
    __syncthreads();
    for (int off = 1; off < 1024; off <<= 1) {
        int add = (t >= off) ? sm[t - off] : 0;
        __syncthreads();
        sm[t] += add;
        __syncthreads();
    }
    if (g < n) incl[g] = sm[t];
    if (t == 1023) bsum[blockIdx.x] = sm[t];
}

__global__ __launch_bounds__(1024) void k_scan2(int* __restrict__ bsum, int nb) {
    __shared__ int sm[1024];
    int t = threadIdx.x;
    int x = (t < nb) ? bsum[t] : 0;
    sm[t] = x;
    __syncthreads();
    for (int off = 1; off < 1024; off <<= 1) {
        int add = (t >= off) ? sm[t - off] : 0;
        __syncthreads();
        sm[t] += add;
        __syncthreads();
    }
    if (t < nb) bsum[t] = sm[t] - x;  // exclusive
}

// exclusive result + sentinel at [n]
__global__ __launch_bounds__(1024) void k_scan3(const int* __restrict__ incl,
                                                const int* __restrict__ bsumx,
                                                const int* __restrict__ v,
                                                int* __restrict__ sOff, int n) {
    int g = blockIdx.x * 1024 + threadIdx.x;
    if (g < n) {
        int inc = incl[g] + bsumx[blockIdx.x];
        sOff[g] = inc - v[g];
        if (g == n - 1) sOff[n] = inc;
    }
}

// ---------------------------------------------------------------------------
// deterministic scatter: LDS cursors, fire-and-forget stores
// ---------------------------------------------------------------------------
__global__ __launch_bounds__(256) void k_scatter(const int* __restrict__ src,
                                                 const int* __restrict__ dst,
                                                 const int* __restrict__ sOff,
                                                 unsigned int* __restrict__ pairs,
                                                 int E, int NB, int chunk) {
    __shared__ int cur[1024];
    int blk = blockIdx.x;
    int cm = (blk & 7) * (SBL / 8) + (blk >> 3);
    for (int b = threadIdx.x; b < NB; b += 256) cur[b] = sOff[b * SBL + cm];
    __syncthreads();
    int beg = blk * chunk, end = min(E, beg + chunk);
    for (int e = beg + threadIdx.x; e < end; e += 256) {
        int d = dst[e];
        int b = d >> BKT_BITS;
        int pos = atomicAdd(&cur[b], 1);
        pairs[pos] = ((unsigned)(d & (BKT - 1)) << 26) | (unsigned)src[e];
    }
}

// ---------------------------------------------------------------------------
// h = x @ W   (f32, 64-row tile per block)
// ---------------------------------------------------------------------------
__global__ __launch_bounds__(256) void k_gemm(const float* __restrict__ x,
                                              const float* __restrict__ W,
                                              float* __restrict__ h, int n) {
    __shared__ float xs[64][128];
    int t = threadIdx.x;
    int rowBase = blockIdx.x * 64;
    for (int i = t; i < 64 * 32; i += 256) {
        int r = i >> 5, c4 = i & 31;
        float4 v = {0.f, 0.f, 0.f, 0.f};
        if (rowBase + r < n)
            v = *(const float4*)(x + (size_t)(rowBase + r) * INCH + c4 * 4);
        *(float4*)&xs[r][c4 * 4] = v;
    }
    __syncthreads();

    int colg = t & 31;
    int rowg = t >> 5;
    float acc[8][4] = {};
    const float4* W4 = (const float4*)W;
    for (int k = 0; k < 128; ++k) {
        float4 w = W4[k * 32 + colg];
#pragma unroll
        for (int i = 0; i < 8; ++i) {
            float xv = xs[rowg * 8 + i][k];
            acc[i][0] = fmaf(xv, w.x, acc[i][0]);
            acc[i][1] = fmaf(xv, w.y, acc[i][1]);
            acc[i][2] = fmaf(xv, w.z, acc[i][2]);
            acc[i][3] = fmaf(xv, w.w, acc[i][3]);
        }
    }
#pragma unroll
    for (int i = 0; i < 8; ++i) {
        int r = rowBase + rowg * 8 + i;
        if (r < n)
            *(float4*)(h + (size_t)r * OUTCH + colg * 4) = *(float4*)acc[i];
    }
}

// ---------------------------------------------------------------------------
// per-node attention logits
// ---------------------------------------------------------------------------
__global__ __launch_bounds__(256) void k_logits(const float* __restrict__ h,
                                                const float* __restrict__ att_src,
                                                const float* __restrict__ att_dst,
                                                float* __restrict__ a_src,
                                                float* __restrict__ a_dst, int n) {
    int t = blockIdx.x * 256 + threadIdx.x;
    int i = t >> 2, head = t & 3;
    if (i >= n) return;
    const float4* hv = (const float4*)(h + (size_t)i * OUTCH + head * C);
    const float4* as4 = (const float4*)(att_src + head * C);
    const float4* ad4 = (const float4*)(att_dst + head * C);
    float ssum = 0.f, dsum = 0.f;
#pragma unroll
    for (int j = 0; j < 8; ++j) {
        float4 v = hv[j], a = as4[j], b = ad4[j];
        ssum += v.x * a.x + v.y * a.y + v.z * a.z + v.w * a.w;
        dsum += v.x * b.x + v.y * b.y + v.z * b.z + v.w * b.w;
    }
    a_src[(size_t)i * 4 + head] = ssum;
    a_dst[(size_t)i * 4 + head] = dsum;
}

// ---------------------------------------------------------------------------
// fused bucket aggregation: one block per bucket of 64 dst nodes.
// LDS f32 accumulators; softmax denom fused; self-loop in epilogue.
// Each wave processes one edge: lane ch = {lane, lane+64}.
// ---------------------------------------------------------------------------
__global__ __launch_bounds__(256) void k_baggr(const float* __restrict__ h,
                                               const float* __restrict__ a_src,
                                               const float* __restrict__ a_dst,
                                               const int* __restrict__ sOff,
                                               const unsigned int* __restrict__ pairs,
                                               const float* __restrict__ bias,
                                               float* __restrict__ out, int n, int NB) {
    __shared__ float acc[BKT * 128];  // 32 KB
    __shared__ float den[BKT * 4];
    __shared__ float exsm[BKT * 4];
    int b = blockIdx.x;
    int t = threadIdx.x;
    for (int i = t; i < BKT * 128; i += 256) acc[i] = 0.f;
    for (int i = t; i < BKT * 4; i += 256) den[i] = 0.f;
    __syncthreads();

    int start = sOff[b * SBL];
    int end   = sOff[(b + 1) * SBL];  // sentinel covers last bucket
    int wave = t >> 6, lane = t & 63;
    int n0 = b << BKT_BITS;
    int h0 = lane >> 5;  // head for ch=lane; ch=lane+64 -> head 2+h0

    for (int e = start + wave; e < end; e += 4) {
        unsigned p = pairs[e];
        int local = p >> 26;
        int s = p & 0x3FFFFFF;
        float ad0 = a_dst[(size_t)(n0 + local) * 4 + h0];
        float ad1 = a_dst[(size_t)(n0 + local) * 4 + 2 + h0];
        float as0 = a_src[(size_t)s * 4 + h0];
        float as1 = a_src[(size_t)s * 4 + 2 + h0];
        float b0 = as0 + ad0; b0 = b0 > 0.f ? b0 : NEG_SLOPE * b0;
        float b1 = as1 + ad1; b1 = b1 > 0.f ? b1 : NEG_SLOPE * b1;
        float e0 = __expf(b0), e1 = __expf(b1);
        float hv0 = h[(size_t)s * OUTCH + lane];
        float hv1 = h[(size_t)s * OUTCH + 64 + lane];
        atomicAdd(&acc[local * 128 + lane], e0 * hv0);
        atomicAdd(&acc[local * 128 + 64 + lane], e1 * hv1);
        if ((lane & 31) == 0) {
            atomicAdd(&den[local * 4 + h0], e0);
            atomicAdd(&den[local * 4 + 2 + h0], e1);
        }
    }
    __syncthreads();

    // self-loop terms
    if (t < BKT * 4) {
        int node = n0 + (t >> 2), hd = t & 3;
        float exs = 0.f;
        if (node < n) {
            float al = a_src[(size_t)node * 4 + hd] + a_dst[(size_t)node * 4 + hd];
            al = al > 0.f ? al : NEG_SLOPE * al;
            exs = __expf(al);
        }
        exsm[t] = exs;
        den[t] += exs;
    }
    __syncthreads();

    for (int i = t; i < BKT * 128; i += 256) {
        int local = i >> 7, ch = i & 127, hd = ch >> 5;
        int node = n0 + local;
        if (node < n) {
            float exs = exsm[local * 4 + hd];
            float v = (acc[i] + exs * h[(size_t)node * OUTCH + ch]) / den[local * 4 + hd]
                      + bias[ch];
            out[(size_t)node * OUTCH + ch] = v;
        }
    }
}

// ---------------------------------------------------------------------------
extern "C" void kernel_launch(void* const* d_in, const int* in_sizes, int n_in,
                              void* d_out, int out_size, void* d_ws, size_t ws_size,
                              hipStream_t stream) {
    const float* x       = (const float*)d_in[0];
    const int*   edge    = (const int*)d_in[1];
    const float* W       = (const float*)d_in[2];
    const float* att_src = (const float*)d_in[3];
    const float* att_dst = (const float*)d_in[4];
    const float* bias    = (const float*)d_in[5];
    float* out = (float*)d_out;

    const int N = in_sizes[0] / INCH;
    const int E = in_sizes[1] / 2;
    const int* esrc = edge;
    const int* edst = edge + E;

    const int NB = (N + BKT - 1) >> BKT_BITS;   // <= 1024 required
    const int n2 = NB * SBL;                    // scan length
    const int chunk = (E + SBL - 1) / SBL;

    auto align = [](size_t v) { return (v + 255) & ~(size_t)255; };
    char* p = (char*)d_ws;
    float* h      = (float*)p; p += align((size_t)N * OUTCH * 4);
    float* a_src  = (float*)p; p += align((size_t)N * 4 * 4);
    float* a_dst  = (float*)p; p += align((size_t)N * 4 * 4);
    int*   hist   = (int*)p;   p += align((size_t)n2 * 4);
    int*   incl   = (int*)p;   p += align((size_t)n2 * 4);
    int*   sOff   = (int*)p;   p += align((size_t)(n2 + 1) * 4);
    int*   bsum   = (int*)p;   p += align(1024 * 4);
    unsigned int* pairs = (unsigned int*)p; p += align((size_t)E * 4);

    const int SCB = (n2 + 1023) / 1024;  // <= 1024

    k_hist<<<SBL, 256, 0, stream>>>(edst, hist, E, NB, chunk);
    k_scan1<<<SCB, 1024, 0, stream>>>(hist, incl, bsum, n2);
    k_scan2<<<1, 1024, 0, stream>>>(bsum, SCB);
    k_scan3<<<SCB, 1024, 0, stream>>>(incl, bsum, hist, sOff, n2);
    k_scatter<<<SBL, 256, 0, stream>>>(esrc, edst, sOff, pairs, E, NB, chunk);

    k_gemm<<<(N + 63) / 64, 256, 0, stream>>>(x, W, h, N);
    k_logits<<<(N * 4 + 255) / 256, 256, 0, stream>>>(h, att_src, att_dst, a_src, a_dst, N);
    k_baggr<<<NB, 256, 0, stream>>>(h, a_src, a_dst, sOff, pairs, bias, out, N, NB);
}

// Round 6
// 273.295 us; speedup vs baseline: 5.6862x; 5.6862x over previous
//
#include <hip/hip_runtime.h>
#include <hip/hip_bf16.h>

#define HEADS 4
#define C 32
#define OUTCH 128   // HEADS*C
#define INCH 128
#define NEG_SLOPE 0.2f

#define BKT 64        // dst nodes per bucket
#define BKT_BITS 6
#define SBL 256       // scatter blocks

// ---------------------------------------------------------------------------
// per-(bucket,block) histogram — no global atomics
// ---------------------------------------------------------------------------
__global__ __launch_bounds__(256) void k_hist(const int* __restrict__ dst,
                                              int* __restrict__ hist,
                                              int E, int NB, int chunk) {
    __shared__ int lh[1024];
    int blk = blockIdx.x;
    for (int i = threadIdx.x; i < NB; i += 256) lh[i] = 0;
    __syncthreads();
    int beg = blk * chunk, end = min(E, beg + chunk);
    for (int e = beg + threadIdx.x; e < end; e += 256)
        atomicAdd(&lh[dst[e] >> BKT_BITS], 1);
    __syncthreads();
    // XCD-major column so adjacent segments come from same-XCD blocks
    int cm = (blk & 7) * (SBL / 8) + (blk >> 3);
    for (int b = threadIdx.x; b < NB; b += 256) hist[b * SBL + cm] = lh[b];
}

// ---------------------------------------------------------------------------
// scan over NB*SBL entries (3 kernels)
// ---------------------------------------------------------------------------
__global__ __launch_bounds__(1024) void k_scan1(const int* __restrict__ v,
                                                int* __restrict__ incl,
                                                int* __restrict__ bsum, int n) {
    __shared__ int sm[1024];
    int t = threadIdx.x;
    int g = blockIdx.x * 1024 + t;
    int x = (g < n) ? v[g] : 0;
    sm[t] = x;
    __syncthreads();
    for (int off = 1; off < 1024; off <<= 1) {
        int add = (t >= off) ? sm[t - off] : 0;
        __syncthreads();
        sm[t] += add;
        __syncthreads();
    }
    if (g < n) incl[g] = sm[t];
    if (t == 1023) bsum[blockIdx.x] = sm[t];
}

__global__ __launch_bounds__(1024) void k_scan2(int* __restrict__ bsum, int nb) {
    __shared__ int sm[1024];
    int t = threadIdx.x;
    int x = (t < nb) ? bsum[t] : 0;
    sm[t] = x;
    __syncthreads();
    for (int off = 1; off < 1024; off <<= 1) {
        int add = (t >= off) ? sm[t - off] : 0;
        __syncthreads();
        sm[t] += add;
        __syncthreads();
    }
    if (t < nb) bsum[t] = sm[t] - x;  // exclusive
}

// exclusive result + sentinel at [n]
__global__ __launch_bounds__(1024) void k_scan3(const int* __restrict__ incl,
                                                const int* __restrict__ bsumx,
                                                const int* __restrict__ v,
                                                int* __restrict__ sOff, int n) {
    int g = blockIdx.x * 1024 + threadIdx.x;
    if (g < n) {
        int inc = incl[g] + bsumx[blockIdx.x];
        sOff[g] = inc - v[g];
        if (g == n - 1) sOff[n] = inc;
    }
}

// ---------------------------------------------------------------------------
// deterministic scatter: LDS cursors, fire-and-forget stores
// ---------------------------------------------------------------------------
__global__ __launch_bounds__(256) void k_scatter(const int* __restrict__ src,
                                                 const int* __restrict__ dst,
                                                 const int* __restrict__ sOff,
                                                 unsigned int* __restrict__ pairs,
                                                 int E, int NB, int chunk) {
    __shared__ int cur[1024];
    int blk = blockIdx.x;
    int cm = (blk & 7) * (SBL / 8) + (blk >> 3);
    for (int b = threadIdx.x; b < NB; b += 256) cur[b] = sOff[b * SBL + cm];
    __syncthreads();
    int beg = blk * chunk, end = min(E, beg + chunk);
    for (int e = beg + threadIdx.x; e < end; e += 256) {
        int d = dst[e];
        int b = d >> BKT_BITS;
        int pos = atomicAdd(&cur[b], 1);
        pairs[pos] = ((unsigned)(d & (BKT - 1)) << 26) | (unsigned)src[e];
    }
}

// ---------------------------------------------------------------------------
// bucket-local fine sort -> node-sorted CSR (srcl) + per-node offs/deg.
// One block per bucket; the bucket's pairs segment is CONTIGUOUS.
// ---------------------------------------------------------------------------
__global__ __launch_bounds__(256) void k_bfill(const unsigned int* __restrict__ pairs,
                                               const int* __restrict__ sOff,
                                               int* __restrict__ offs,
                                               int* __restrict__ deg,
                                               int* __restrict__ srcl, int n) {
    __shared__ int hist64[64];
    __shared__ int cur[64];
    int b = blockIdx.x;
    int t = threadIdx.x;
    int start = sOff[b * SBL];
    int end   = sOff[(b + 1) * SBL];
    if (t < 64) hist64[t] = 0;
    __syncthreads();
    for (int i = start + t; i < end; i += 256)
        atomicAdd(&hist64[pairs[i] >> 26], 1);
    __syncthreads();
    if (t < 64) {
        int v = hist64[t];
        int incl = v;
        for (int off = 1; off < 64; off <<= 1) {
            int u = __shfl_up(incl, off);
            if (t >= off) incl += u;
        }
        int excl = incl - v;
        cur[t] = start + excl;
        int node = (b << BKT_BITS) + t;
        if (node < n) { offs[node] = start + excl; deg[node] = v; }
    }
    __syncthreads();
    for (int i = start + t; i < end; i += 256) {
        unsigned p = pairs[i];
        int pos = atomicAdd(&cur[p >> 26], 1);
        srcl[pos] = p & 0x3FFFFFF;
    }
}

// ---------------------------------------------------------------------------
// h = x @ W  with fused attention logits (epilogue shuffle-reduce)
// ---------------------------------------------------------------------------
__global__ __launch_bounds__(256) void k_gemm(const float* __restrict__ x,
                                              const float* __restrict__ W,
                                              const float* __restrict__ att_src,
                                              const float* __restrict__ att_dst,
                                              float* __restrict__ h,
                                              float* __restrict__ a_src,
                                              float* __restrict__ a_dst, int n) {
    __shared__ float xs[64][128];
    int t = threadIdx.x;
    int rowBase = blockIdx.x * 64;
    for (int i = t; i < 64 * 32; i += 256) {
        int r = i >> 5, c4 = i & 31;
        float4 v = {0.f, 0.f, 0.f, 0.f};
        if (rowBase + r < n)
            v = *(const float4*)(x + (size_t)(rowBase + r) * INCH + c4 * 4);
        *(float4*)&xs[r][c4 * 4] = v;
    }
    __syncthreads();

    int colg = t & 31;
    int rowg = t >> 5;
    float acc[8][4] = {};
    const float4* W4 = (const float4*)W;
    for (int k = 0; k < 128; ++k) {
        float4 w = W4[k * 32 + colg];
#pragma unroll
        for (int i = 0; i < 8; ++i) {
            float xv = xs[rowg * 8 + i][k];
            acc[i][0] = fmaf(xv, w.x, acc[i][0]);
            acc[i][1] = fmaf(xv, w.y, acc[i][1]);
            acc[i][2] = fmaf(xv, w.z, acc[i][2]);
            acc[i][3] = fmaf(xv, w.w, acc[i][3]);
        }
    }

    int head = colg >> 3;
    float as4[4], ad4[4];
#pragma unroll
    for (int c = 0; c < 4; ++c) {
        int within = (colg & 7) * 4 + c;
        as4[c] = att_src[head * C + within];
        ad4[c] = att_dst[head * C + within];
    }
#pragma unroll
    for (int i = 0; i < 8; ++i) {
        int r = rowBase + rowg * 8 + i;
        if (r < n)
            *(float4*)(h + (size_t)r * OUTCH + colg * 4) = *(float4*)acc[i];
        float ps = acc[i][0] * as4[0] + acc[i][1] * as4[1] +
                   acc[i][2] * as4[2] + acc[i][3] * as4[3];
        float pd = acc[i][0] * ad4[0] + acc[i][1] * ad4[1] +
                   acc[i][2] * ad4[2] + acc[i][3] * ad4[3];
        ps += __shfl_xor(ps, 1); ps += __shfl_xor(ps, 2); ps += __shfl_xor(ps, 4);
        pd += __shfl_xor(pd, 1); pd += __shfl_xor(pd, 2); pd += __shfl_xor(pd, 4);
        if ((colg & 7) == 0 && r < n) {
            a_src[(size_t)r * 4 + head] = ps;
            a_dst[(size_t)r * 4 + head] = pd;
        }
    }
}

// ---------------------------------------------------------------------------
// aggregation: wave per node, half-wave per edge (float4/lane), 2-way unroll.
// ---------------------------------------------------------------------------
__global__ __launch_bounds__(256) void k_aggr(const float* __restrict__ h,
                                              const float* __restrict__ a_src,
                                              const float* __restrict__ a_dst,
                                              const int* __restrict__ offs,
                                              const int* __restrict__ deg,
                                              const int* __restrict__ srcl,
                                              const float* __restrict__ bias,
                                              float* __restrict__ out, int n) {
    int w = (blockIdx.x * 256 + threadIdx.x) >> 6;
    if (w >= n) return;
    int lane = threadIdx.x & 63;
    int half = lane >> 5;
    int l32 = lane & 31;
    int head = l32 >> 3;
    int ch4 = l32 * 4;

    float adst = a_dst[(size_t)w * 4 + head];
    float f0 = 0.f, f1 = 0.f, f2 = 0.f, f3 = 0.f, fden = 0.f;

    if (half == 0) {  // self-loop on half 0 only
        float al = a_src[(size_t)w * 4 + head] + adst;
        al = al > 0.f ? al : NEG_SLOPE * al;
        float ex = __expf(al);
        float4 hv = *(const float4*)(h + (size_t)w * OUTCH + ch4);
        f0 = ex * hv.x; f1 = ex * hv.y; f2 = ex * hv.z; f3 = ex * hv.w;
        fden = ex;
    }

    int start = offs[w], d = deg[w];
    int j = half;
    for (; j + 2 < d; j += 4) {
        int s0 = srcl[start + j];
        int s1 = srcl[start + j + 2];
        float as0 = a_src[(size_t)s0 * 4 + head];
        float as1 = a_src[(size_t)s1 * 4 + head];
        float4 h0 = *(const float4*)(h + (size_t)s0 * OUTCH + ch4);
        float4 h1 = *(const float4*)(h + (size_t)s1 * OUTCH + ch4);
        float b0 = as0 + adst; b0 = b0 > 0.f ? b0 : NEG_SLOPE * b0;
        float b1 = as1 + adst; b1 = b1 > 0.f ? b1 : NEG_SLOPE * b1;
        float e0 = __expf(b0), e1 = __expf(b1);
        fden += e0 + e1;
        f0 = fmaf(e0, h0.x, f0); f1 = fmaf(e0, h0.y, f1);
        f2 = fmaf(e0, h0.z, f2); f3 = fmaf(e0, h0.w, f3);
        f0 = fmaf(e1, h1.x, f0); f1 = fmaf(e1, h1.y, f1);
        f2 = fmaf(e1, h1.z, f2); f3 = fmaf(e1, h1.w, f3);
    }
    if (j < d) {
        int s0 = srcl[start + j];
        float as0 = a_src[(size_t)s0 * 4 + head];
        float4 h0 = *(const float4*)(h + (size_t)s0 * OUTCH + ch4);
        float b0 = as0 + adst; b0 = b0 > 0.f ? b0 : NEG_SLOPE * b0;
        float e0 = __expf(b0);
        fden += e0;
        f0 = fmaf(e0, h0.x, f0); f1 = fmaf(e0, h0.y, f1);
        f2 = fmaf(e0, h0.z, f2); f3 = fmaf(e0, h0.w, f3);
    }

    // combine halves
    f0 += __shfl_xor(f0, 32);
    f1 += __shfl_xor(f1, 32);
    f2 += __shfl_xor(f2, 32);
    f3 += __shfl_xor(f3, 32);
    fden += __shfl_xor(fden, 32);

    if (half == 0) {
        float inv = 1.0f / fden;
        float4 bv = *(const float4*)(bias + ch4);
        float4 o;
        o.x = f0 * inv + bv.x;
        o.y = f1 * inv + bv.y;
        o.z = f2 * inv + bv.z;
        o.w = f3 * inv + bv.w;
        *(float4*)(out + (size_t)w * OUTCH + ch4) = o;
    }
}

// ---------------------------------------------------------------------------
extern "C" void kernel_launch(void* const* d_in, const int* in_sizes, int n_in,
                              void* d_out, int out_size, void* d_ws, size_t ws_size,
                              hipStream_t stream) {
    const float* x       = (const float*)d_in[0];
    const int*   edge    = (const int*)d_in[1];
    const float* W       = (const float*)d_in[2];
    const float* att_src = (const float*)d_in[3];
    const float* att_dst = (const float*)d_in[4];
    const float* bias    = (const float*)d_in[5];
    float* out = (float*)d_out;

    const int N = in_sizes[0] / INCH;
    const int E = in_sizes[1] / 2;
    const int* esrc = edge;
    const int* edst = edge + E;

    const int NB = (N + BKT - 1) >> BKT_BITS;   // buckets (<=1024)
    const int n2 = NB * SBL;                    // scan length
    const int chunk = (E + SBL - 1) / SBL;

    auto align = [](size_t v) { return (v + 255) & ~(size_t)255; };
    char* p = (char*)d_ws;
    float* h      = (float*)p; p += align((size_t)N * OUTCH * 4);
    float* a_src  = (float*)p; p += align((size_t)N * 4 * 4);
    float* a_dst  = (float*)p; p += align((size_t)N * 4 * 4);
    int*   hist   = (int*)p;   p += align((size_t)n2 * 4);
    int*   incl   = (int*)p;   p += align((size_t)(n2 + 1) * 4);
    int*   sOff   = (int*)p;   p += align((size_t)(n2 + 1) * 4);
    int*   bsum   = (int*)p;   p += align(1024 * 4);
    int*   offs   = (int*)p;   p += align((size_t)N * 4);
    int*   deg    = (int*)p;   p += align((size_t)N * 4);
    unsigned int* pairs = (unsigned int*)p; p += align((size_t)E * 4);
    int*   srcl   = (int*)p;   p += align((size_t)E * 4);

    const int SCB = (n2 + 1023) / 1024;

    k_hist<<<SBL, 256, 0, stream>>>(edst, hist, E, NB, chunk);
    k_scan1<<<SCB, 1024, 0, stream>>>(hist, incl, bsum, n2);
    k_scan2<<<1, 1024, 0, stream>>>(bsum, SCB);
    k_scan3<<<SCB, 1024, 0, stream>>>(incl, bsum, hist, sOff, n2);
    k_scatter<<<SBL, 256, 0, stream>>>(esrc, edst, sOff, pairs, E, NB, chunk);
    k_bfill<<<NB, 256, 0, stream>>>(pairs, sOff, offs, deg, srcl, N);

    k_gemm<<<(N + 63) / 64, 256, 0, stream>>>(x, W, att_src, att_dst, h, a_src, a_dst, N);
    k_aggr<<<(N + 3) / 4, 256, 0, stream>>>(h, a_src, a_dst, offs, deg, srcl, bias, out, N);
}

// Round 7
// 229.673 us; speedup vs baseline: 6.7662x; 1.1899x over previous
//
#include <hip/hip_runtime.h>
#include <hip/hip_bf16.h>
#include <hip/hip_fp16.h>

#define HEADS 4
#define C 32
#define OUTCH 128   // HEADS*C
#define INCH 128
#define NEG_SLOPE 0.2f

#define BKT 64        // dst nodes per bucket
#define BKT_BITS 6
#define SBL 256       // scatter blocks

struct alignas(8) h2x2 { __half2 a, b; };

// ---------------------------------------------------------------------------
// per-(bucket,block) histogram — no global atomics
// ---------------------------------------------------------------------------
__global__ __launch_bounds__(256) void k_hist(const int* __restrict__ dst,
                                              int* __restrict__ hist,
                                              int E, int NB, int chunk) {
    __shared__ int lh[1024];
    int blk = blockIdx.x;
    for (int i = threadIdx.x; i < NB; i += 256) lh[i] = 0;
    __syncthreads();
    int beg = blk * chunk, end = min(E, beg + chunk);
    for (int e = beg + threadIdx.x; e < end; e += 256)
        atomicAdd(&lh[dst[e] >> BKT_BITS], 1);
    __syncthreads();
    // XCD-major column so adjacent segments come from same-XCD blocks
    int cm = (blk & 7) * (SBL / 8) + (blk >> 3);
    for (int b = threadIdx.x; b < NB; b += 256) hist[b * SBL + cm] = lh[b];
}

// ---------------------------------------------------------------------------
// scan over NB*SBL entries (3 kernels)
// ---------------------------------------------------------------------------
__global__ __launch_bounds__(1024) void k_scan1(const int* __restrict__ v,
                                                int* __restrict__ incl,
                                                int* __restrict__ bsum, int n) {
    __shared__ int sm[1024];
    int t = threadIdx.x;
    int g = blockIdx.x * 1024 + t;
    int x = (g < n) ? v[g] : 0;
    sm[t] = x;
    __syncthreads();
    for (int off = 1; off < 1024; off <<= 1) {
        int add = (t >= off) ? sm[t - off] : 0;
        __syncthreads();
        sm[t] += add;
        __syncthreads();
    }
    if (g < n) incl[g] = sm[t];
    if (t == 1023) bsum[blockIdx.x] = sm[t];
}

__global__ __launch_bounds__(1024) void k_scan2(int* __restrict__ bsum, int nb) {
    __shared__ int sm[1024];
    int t = threadIdx.x;
    int x = (t < nb) ? bsum[t] : 0;
    sm[t] = x;
    __syncthreads();
    for (int off = 1; off < 1024; off <<= 1) {
        int add = (t >= off) ? sm[t - off] : 0;
        __syncthreads();
        sm[t] += add;
        __syncthreads();
    }
    if (t < nb) bsum[t] = sm[t] - x;  // exclusive
}

// exclusive result + sentinel at [n]
__global__ __launch_bounds__(1024) void k_scan3(const int* __restrict__ incl,
                                                const int* __restrict__ bsumx,
                                                const int* __restrict__ v,
                                                int* __restrict__ sOff, int n) {
    int g = blockIdx.x * 1024 + threadIdx.x;
    if (g < n) {
        int inc = incl[g] + bsumx[blockIdx.x];
        sOff[g] = inc - v[g];
        if (g == n - 1) sOff[n] = inc;
    }
}

// ---------------------------------------------------------------------------
// deterministic scatter: LDS cursors, fire-and-forget stores
// ---------------------------------------------------------------------------
__global__ __launch_bounds__(256) void k_scatter(const int* __restrict__ src,
                                                 const int* __restrict__ dst,
                                                 const int* __restrict__ sOff,
                                                 unsigned int* __restrict__ pairs,
                                                 int E, int NB, int chunk) {
    __shared__ int cur[1024];
    int blk = blockIdx.x;
    int cm = (blk & 7) * (SBL / 8) + (blk >> 3);
    for (int b = threadIdx.x; b < NB; b += 256) cur[b] = sOff[b * SBL + cm];
    __syncthreads();
    int beg = blk * chunk, end = min(E, beg + chunk);
    for (int e = beg + threadIdx.x; e < end; e += 256) {
        int d = dst[e];
        int b = d >> BKT_BITS;
        int pos = atomicAdd(&cur[b], 1);
        pairs[pos] = ((unsigned)(d & (BKT - 1)) << 26) | (unsigned)src[e];
    }
}

// ---------------------------------------------------------------------------
// bucket-local fine sort -> node-sorted CSR (srcl) + per-node offs/deg.
// ---------------------------------------------------------------------------
__global__ __launch_bounds__(256) void k_bfill(const unsigned int* __restrict__ pairs,
                                               const int* __restrict__ sOff,
                                               int* __restrict__ offs,
                                               int* __restrict__ deg,
                                               int* __restrict__ srcl, int n) {
    __shared__ int hist64[64];
    __shared__ int cur[64];
    int b = blockIdx.x;
    int t = threadIdx.x;
    int start = sOff[b * SBL];
    int end   = sOff[(b + 1) * SBL];
    if (t < 64) hist64[t] = 0;
    __syncthreads();
    for (int i = start + t; i < end; i += 256)
        atomicAdd(&hist64[pairs[i] >> 26], 1);
    __syncthreads();
    if (t < 64) {
        int v = hist64[t];
        int incl = v;
        for (int off = 1; off < 64; off <<= 1) {
            int u = __shfl_up(incl, off);
            if (t >= off) incl += u;
        }
        int excl = incl - v;
        cur[t] = start + excl;
        int node = (b << BKT_BITS) + t;
        if (node < n) { offs[node] = start + excl; deg[node] = v; }
    }
    __syncthreads();
    for (int i = start + t; i < end; i += 256) {
        unsigned p = pairs[i];
        int pos = atomicAdd(&cur[p >> 26], 1);
        srcl[pos] = p & 0x3FFFFFF;
    }
}

// ---------------------------------------------------------------------------
// h16 = fp16(x @ W), fused attention logits (f32 accumulators, shuffle-reduce)
// ---------------------------------------------------------------------------
__global__ __launch_bounds__(256) void k_gemm(const float* __restrict__ x,
                                              const float* __restrict__ W,
                                              const float* __restrict__ att_src,
                                              const float* __restrict__ att_dst,
                                              __half* __restrict__ h16,
                                              float* __restrict__ a_src,
                                              float* __restrict__ a_dst, int n) {
    __shared__ float xs[64][128];
    int t = threadIdx.x;
    int rowBase = blockIdx.x * 64;
    for (int i = t; i < 64 * 32; i += 256) {
        int r = i >> 5, c4 = i & 31;
        float4 v = {0.f, 0.f, 0.f, 0.f};
        if (rowBase + r < n)
            v = *(const float4*)(x + (size_t)(rowBase + r) * INCH + c4 * 4);
        *(float4*)&xs[r][c4 * 4] = v;
    }
    __syncthreads();

    int colg = t & 31;
    int rowg = t >> 5;
    float acc[8][4] = {};
    const float4* W4 = (const float4*)W;
    for (int k = 0; k < 128; ++k) {
        float4 w = W4[k * 32 + colg];
#pragma unroll
        for (int i = 0; i < 8; ++i) {
            float xv = xs[rowg * 8 + i][k];
            acc[i][0] = fmaf(xv, w.x, acc[i][0]);
            acc[i][1] = fmaf(xv, w.y, acc[i][1]);
            acc[i][2] = fmaf(xv, w.z, acc[i][2]);
            acc[i][3] = fmaf(xv, w.w, acc[i][3]);
        }
    }

    int head = colg >> 3;
    float as4[4], ad4[4];
#pragma unroll
    for (int c = 0; c < 4; ++c) {
        int within = (colg & 7) * 4 + c;
        as4[c] = att_src[head * C + within];
        ad4[c] = att_dst[head * C + within];
    }
#pragma unroll
    for (int i = 0; i < 8; ++i) {
        int r = rowBase + rowg * 8 + i;
        if (r < n) {
            h2x2 pk;
            pk.a = __floats2half2_rn(acc[i][0], acc[i][1]);
            pk.b = __floats2half2_rn(acc[i][2], acc[i][3]);
            *(h2x2*)(h16 + (size_t)r * OUTCH + colg * 4) = pk;
        }
        float ps = acc[i][0] * as4[0] + acc[i][1] * as4[1] +
                   acc[i][2] * as4[2] + acc[i][3] * as4[3];
        float pd = acc[i][0] * ad4[0] + acc[i][1] * ad4[1] +
                   acc[i][2] * ad4[2] + acc[i][3] * ad4[3];
        ps += __shfl_xor(ps, 1); ps += __shfl_xor(ps, 2); ps += __shfl_xor(ps, 4);
        pd += __shfl_xor(pd, 1); pd += __shfl_xor(pd, 2); pd += __shfl_xor(pd, 4);
        if ((colg & 7) == 0 && r < n) {
            a_src[(size_t)r * 4 + head] = ps;
            a_dst[(size_t)r * 4 + head] = pd;
        }
    }
}

// ---------------------------------------------------------------------------
// aggregation: one wave per node; full wave per edge (64 lanes x half2 = 256B
// coalesced row); denominator lane-redundant per head group; 4-way unroll.
// ---------------------------------------------------------------------------
__global__ __launch_bounds__(256) void k_aggr(const __half* __restrict__ h16,
                                              const float* __restrict__ a_src,
                                              const float* __restrict__ a_dst,
                                              const int* __restrict__ offs,
                                              const int* __restrict__ deg,
                                              const int* __restrict__ srcl,
                                              const float* __restrict__ bias,
                                              float* __restrict__ out, int n) {
    int w = (blockIdx.x * 256 + threadIdx.x) >> 6;
    if (w >= n) return;
    int lane = threadIdx.x & 63;
    int head = lane >> 4;   // 16 lanes (32 ch) per head
    int ch = lane << 1;
    const __half2* H2 = (const __half2*)h16;  // row stride 64

    float adst = a_dst[(size_t)w * 4 + head];

    // self-loop
    float al = a_src[(size_t)w * 4 + head] + adst;
    al = al > 0.f ? al : NEG_SLOPE * al;
    float ex = __expf(al);
    float2 hv = __half22float2(H2[(size_t)w * 64 + lane]);
    float f0 = ex * hv.x, f1 = ex * hv.y, den = ex;

    int start = offs[w], d = deg[w];
    int j = 0;
    for (; j + 4 <= d; j += 4) {
        int s0 = srcl[start + j];
        int s1 = srcl[start + j + 1];
        int s2 = srcl[start + j + 2];
        int s3 = srcl[start + j + 3];
        float b0 = a_src[(size_t)s0 * 4 + head] + adst;
        float b1 = a_src[(size_t)s1 * 4 + head] + adst;
        float b2 = a_src[(size_t)s2 * 4 + head] + adst;
        float b3 = a_src[(size_t)s3 * 4 + head] + adst;
        __half2 g0 = H2[(size_t)s0 * 64 + lane];
        __half2 g1 = H2[(size_t)s1 * 64 + lane];
        __half2 g2 = H2[(size_t)s2 * 64 + lane];
        __half2 g3 = H2[(size_t)s3 * 64 + lane];
        b0 = b0 > 0.f ? b0 : NEG_SLOPE * b0;
        b1 = b1 > 0.f ? b1 : NEG_SLOPE * b1;
        b2 = b2 > 0.f ? b2 : NEG_SLOPE * b2;
        b3 = b3 > 0.f ? b3 : NEG_SLOPE * b3;
        float e0 = __expf(b0), e1 = __expf(b1), e2 = __expf(b2), e3 = __expf(b3);
        den += (e0 + e1) + (e2 + e3);
        float2 G0 = __half22float2(g0);
        float2 G1 = __half22float2(g1);
        float2 G2 = __half22float2(g2);
        float2 G3 = __half22float2(g3);
        f0 = fmaf(e0, G0.x, f0); f1 = fmaf(e0, G0.y, f1);
        f0 = fmaf(e1, G1.x, f0); f1 = fmaf(e1, G1.y, f1);
        f0 = fmaf(e2, G2.x, f0); f1 = fmaf(e2, G2.y, f1);
        f0 = fmaf(e3, G3.x, f0); f1 = fmaf(e3, G3.y, f1);
    }
    for (; j < d; ++j) {
        int s0 = srcl[start + j];
        float b0 = a_src[(size_t)s0 * 4 + head] + adst;
        __half2 g0 = H2[(size_t)s0 * 64 + lane];
        b0 = b0 > 0.f ? b0 : NEG_SLOPE * b0;
        float e0 = __expf(b0);
        den += e0;
        float2 G0 = __half22float2(g0);
        f0 = fmaf(e0, G0.x, f0); f1 = fmaf(e0, G0.y, f1);
    }

    float inv = 1.0f / den;
    float2 bv = *(const float2*)(bias + ch);
    float2 o;
    o.x = f0 * inv + bv.x;
    o.y = f1 * inv + bv.y;
    *(float2*)(out + (size_t)w * OUTCH + ch) = o;
}

// ---------------------------------------------------------------------------
extern "C" void kernel_launch(void* const* d_in, const int* in_sizes, int n_in,
                              void* d_out, int out_size, void* d_ws, size_t ws_size,
                              hipStream_t stream) {
    const float* x       = (const float*)d_in[0];
    const int*   edge    = (const int*)d_in[1];
    const float* W       = (const float*)d_in[2];
    const float* att_src = (const float*)d_in[3];
    const float* att_dst = (const float*)d_in[4];
    const float* bias    = (const float*)d_in[5];
    float* out = (float*)d_out;

    const int N = in_sizes[0] / INCH;
    const int E = in_sizes[1] / 2;
    const int* esrc = edge;
    const int* edst = edge + E;

    const int NB = (N + BKT - 1) >> BKT_BITS;   // buckets (<=1024)
    const int n2 = NB * SBL;                    // scan length
    const int chunk = (E + SBL - 1) / SBL;

    auto align = [](size_t v) { return (v + 255) & ~(size_t)255; };
    char* p = (char*)d_ws;
    __half* h16   = (__half*)p; p += align((size_t)N * OUTCH * 2);
    float* a_src  = (float*)p; p += align((size_t)N * 4 * 4);
    float* a_dst  = (float*)p; p += align((size_t)N * 4 * 4);
    int*   hist   = (int*)p;   p += align((size_t)n2 * 4);
    int*   incl   = (int*)p;   p += align((size_t)(n2 + 1) * 4);
    int*   sOff   = (int*)p;   p += align((size_t)(n2 + 1) * 4);
    int*   bsum   = (int*)p;   p += align(1024 * 4);
    int*   offs   = (int*)p;   p += align((size_t)N * 4);
    int*   deg    = (int*)p;   p += align((size_t)N * 4);
    unsigned int* pairs = (unsigned int*)p; p += align((size_t)E * 4);
    int*   srcl   = (int*)p;   p += align((size_t)E * 4);

    const int SCB = (n2 + 1023) / 1024;

    k_hist<<<SBL, 256, 0, stream>>>(edst, hist, E, NB, chunk);
    k_scan1<<<SCB, 1024, 0, stream>>>(hist, incl, bsum, n2);
    k_scan2<<<1, 1024, 0, stream>>>(bsum, SCB);
    k_scan3<<<SCB, 1024, 0, stream>>>(incl, bsum, hist, sOff, n2);
    k_scatter<<<SBL, 256, 0, stream>>>(esrc, edst, sOff, pairs, E, NB, chunk);
    k_bfill<<<NB, 256, 0, stream>>>(pairs, sOff, offs, deg, srcl, N);

    k_gemm<<<(N + 63) / 64, 256, 0, stream>>>(x, W, att_src, att_dst, h16, a_src, a_dst, N);
    k_aggr<<<(N + 3) / 4, 256, 0, stream>>>(h16, a_src, a_dst, offs, deg, srcl, bias, out, N);
}